// Round 1
// baseline (1120.642 us; speedup 1.0000x reference)
//
#include <hip/hip_runtime.h>

#define B_ 32
#define P_ 4096
#define Q_ 64
#define D_ 128

// workspace layout (floats)
#define T_SIZE (B_*Q_*D_)       // 262144 floats
#define PART_STRIDE 772         // [L, S, v:128, mxH:128, mnH:128, mxC:128, mxHC:128, mxM:128]

// ---------------------------------------------------------------------------
// k_T: T[b,q,d] = sum_e W[d,e] * U[b,q,e]
// grid 256 = 32 b * 8 q-chunks, 256 threads
// ---------------------------------------------------------------------------
__global__ __launch_bounds__(256) void k_T(const float* __restrict__ U,
                                           const float* __restrict__ W,
                                           float* __restrict__ T) {
  __shared__ float Wl[128*132];
  __shared__ float Ul[8*128];
  const int b = blockIdx.x >> 3, qc = blockIdx.x & 7;
  const int t = threadIdx.x;
#pragma unroll
  for (int k = 0; k < 16; ++k) {
    int i = t*4 + k*1024;                 // 16384 floats of W
    float4 wv = *(const float4*)(W + i);
    int d = i >> 7, e = i & 127;
    *(float4*)(&Wl[d*132 + e]) = wv;
  }
  {
    int i = t*4;                          // 1024 floats of U slice
    int q = i >> 7, e = i & 127;
    *(float4*)(&Ul[q*128 + e]) =
        *(const float4*)(U + ((size_t)(b*Q_ + qc*8 + q))*D_ + e);
  }
  __syncthreads();
  const int d = t & 127, qhalf = t >> 7;
#pragma unroll
  for (int pass = 0; pass < 4; ++pass) {
    const int q = pass*2 + qhalf;
    float acc = 0.f;
#pragma unroll
    for (int e = 0; e < 128; e += 4) {
      float4 wv = *(float4*)(&Wl[d*132 + e]);
      float4 uv = *(float4*)(&Ul[q*128 + e]);
      acc += wv.x*uv.x + wv.y*uv.y + wv.z*uv.z + wv.w*uv.w;
    }
    T[((size_t)(b*Q_ + qc*8 + q))*D_ + d] = acc;
  }
}

// ---------------------------------------------------------------------------
// k_main: per (b, 512-row chunk): scores, softmax, c2q, online q2c, masked maxes
// grid 256 = 32 b * 8 chunks, 512 threads (8 waves, 64 rows/wave, groups of 8)
// ---------------------------------------------------------------------------
__global__ __launch_bounds__(512, 1) void k_main(
    const float* __restrict__ H, const float* __restrict__ U,
    const float* __restrict__ M, const int* __restrict__ tok,
    const float* __restrict__ T, float* __restrict__ part) {
  __shared__ float Tl[Q_*132];     // 33792 B, padded stride
  __shared__ float Ul[Q_*D_];      // 32768 B
  __shared__ float Hl[8][1024];    // 32768 B (per-wave H rows; reused as combine scratch)
  __shared__ float wl[8][512];     // 16384 B (per-wave softmax weights)
  const int bid = blockIdx.x;
  const int b = bid >> 3, chunk = bid & 7;
  const int t = threadIdx.x, wv = t >> 6, l = t & 63;
  const float* Tb = T + (size_t)b*Q_*D_;
  const float* Ub = U + (size_t)b*Q_*D_;
#pragma unroll
  for (int k = 0; k < 4; ++k) {
    int i = t*4 + k*2048;                 // 8192 floats each
    int q = i >> 7, d = i & 127;
    *(float4*)(&Tl[q*132 + d]) = *(const float4*)(Tb + i);
    *(float4*)(&Ul[i])         = *(const float4*)(Ub + i);
  }
  __syncthreads();

  const float* Hb = H + (size_t)b*P_*D_;
  const float* Mb = M + (size_t)b*P_*D_;
  const int*  tkb = tok + b*P_;
  float* HlW = Hl[wv];
  float* wlW = wl[wv];

  float Lmax = -3.0e38f, ssum = 0.f, v0 = 0.f, v1 = 0.f;
  float mxH0 = -3.0e38f, mxH1 = -3.0e38f, mnH0 = 3.0e38f, mnH1 = 3.0e38f;
  float mxC0 = -3.0e38f, mxC1 = -3.0e38f, mxHC0 = -3.0e38f, mxHC1 = -3.0e38f;
  float mxM0 = -3.0e38f, mxM1 = -3.0e38f;

  const int rowW = chunk*512 + wv*64;
#pragma unroll 1
  for (int g = 0; g < 8; ++g) {
    const int row0 = rowW + g*8;
    float h0[8], h1[8], m0[8], m1[8];
    int tk[8];
#pragma unroll
    for (int r = 0; r < 8; ++r) {
      const float* hp = Hb + (size_t)(row0 + r)*D_;
      const float* mp = Mb + (size_t)(row0 + r)*D_;
      h0[r] = hp[l];      h1[r] = hp[l + 64];
      m0[r] = mp[l];      m1[r] = mp[l + 64];
      tk[r] = tkb[row0 + r];
    }
#pragma unroll
    for (int r = 0; r < 8; ++r) {
      HlW[r*128 + l]      = h0[r];
      HlW[r*128 + l + 64] = h1[r];
    }
    // ---- scores: lane = q, s[r] = H[row r] . T[q] ----
    float s[8] = {0,0,0,0,0,0,0,0};
#pragma unroll
    for (int d0 = 0; d0 < 128; d0 += 4) {
      float4 tq = *(float4*)(&Tl[l*132 + d0]);
#pragma unroll
      for (int r = 0; r < 8; ++r) {
        float4 hh = *(float4*)(&HlW[r*128 + d0]);
        s[r] += tq.x*hh.x + tq.y*hh.y + tq.z*hh.z + tq.w*hh.w;
      }
    }
    // ---- softmax over q (cross-lane), weights to LDS, online q2c ----
#pragma unroll
    for (int r = 0; r < 8; ++r) {
      float m = s[r];
#pragma unroll
      for (int off = 32; off; off >>= 1) m = fmaxf(m, __shfl_xor(m, off));
      float e = __expf(s[r] - m);
      float sum = e;
#pragma unroll
      for (int off = 32; off; off >>= 1) sum += __shfl_xor(sum, off);
      wlW[r*64 + l] = e / sum;
      // online softmax over row-maxes -> q2c accumulation
      float nm = fmaxf(Lmax, m);
      float so = __expf(Lmax - nm);
      float pr = __expf(m - nm);
      v0 = v0*so + pr*h0[r];
      v1 = v1*so + pr*h1[r];
      ssum = ssum*so + pr;
      Lmax = nm;
    }
    // ---- c2q: lane owns d = {l, l+64} ----
    float c0[8] = {0,0,0,0,0,0,0,0}, c1[8] = {0,0,0,0,0,0,0,0};
#pragma unroll
    for (int q0 = 0; q0 < 64; q0 += 4) {
      float u00 = Ul[(q0+0)*128 + l], u01 = Ul[(q0+0)*128 + l + 64];
      float u10 = Ul[(q0+1)*128 + l], u11 = Ul[(q0+1)*128 + l + 64];
      float u20 = Ul[(q0+2)*128 + l], u21 = Ul[(q0+2)*128 + l + 64];
      float u30 = Ul[(q0+3)*128 + l], u31 = Ul[(q0+3)*128 + l + 64];
#pragma unroll
      for (int r = 0; r < 8; ++r) {
        float4 ww = *(float4*)(&wlW[r*64 + q0]);
        c0[r] += ww.x*u00 + ww.y*u10 + ww.z*u20 + ww.w*u30;
        c1[r] += ww.x*u01 + ww.y*u11 + ww.z*u21 + ww.w*u31;
      }
    }
    // ---- masked pool maxes (token==PAD excluded) ----
#pragma unroll
    for (int r = 0; r < 8; ++r) {
      if (tk[r] != 0) {
        mxH0  = fmaxf(mxH0,  h0[r]);        mxH1  = fmaxf(mxH1,  h1[r]);
        mnH0  = fminf(mnH0,  h0[r]);        mnH1  = fminf(mnH1,  h1[r]);
        mxC0  = fmaxf(mxC0,  c0[r]);        mxC1  = fmaxf(mxC1,  c1[r]);
        mxHC0 = fmaxf(mxHC0, h0[r]*c0[r]);  mxHC1 = fmaxf(mxHC1, h1[r]*c1[r]);
        mxM0  = fmaxf(mxM0,  m0[r]);        mxM1  = fmaxf(mxM1,  m1[r]);
      }
    }
  }
  __syncthreads();
  // per-wave partials into Hl scratch (1024 floats/wave)
  float* sc = &Hl[0][0] + wv*1024;
  if (l == 0) { sc[0] = Lmax; sc[1] = ssum; }
  sc[2 + l]   = v0;     sc[2 + l + 64]   = v1;
  sc[130 + l] = mxH0;   sc[130 + l + 64] = mxH1;
  sc[258 + l] = mnH0;   sc[258 + l + 64] = mnH1;
  sc[386 + l] = mxC0;   sc[386 + l + 64] = mxC1;
  sc[514 + l] = mxHC0;  sc[514 + l + 64] = mxHC1;
  sc[642 + l] = mxM0;   sc[642 + l + 64] = mxM1;
  __syncthreads();
  if (t < 128) {
    const float* s0 = &Hl[0][0];
    float L = -3.0e38f;
#pragma unroll
    for (int w = 0; w < 8; ++w) L = fmaxf(L, s0[w*1024]);
    float S = 0.f, V = 0.f;
    float mh = -3.0e38f, nh = 3.0e38f, mc = -3.0e38f, mhc = -3.0e38f, mm = -3.0e38f;
#pragma unroll
    for (int w = 0; w < 8; ++w) {
      float e = __expf(s0[w*1024] - L);
      S += s0[w*1024 + 1]*e;
      V += s0[w*1024 + 2 + t]*e;
      mh  = fmaxf(mh,  s0[w*1024 + 130 + t]);
      nh  = fminf(nh,  s0[w*1024 + 258 + t]);
      mc  = fmaxf(mc,  s0[w*1024 + 386 + t]);
      mhc = fmaxf(mhc, s0[w*1024 + 514 + t]);
      mm  = fmaxf(mm,  s0[w*1024 + 642 + t]);
    }
    float* pp = part + (size_t)bid*PART_STRIDE;
    if (t == 0) { pp[0] = L; pp[1] = S; }
    pp[2 + t]   = V;
    pp[130 + t] = mh;
    pp[258 + t] = nh;
    pp[386 + t] = mc;
    pp[514 + t] = mhc;
    pp[642 + t] = mm;
  }
}

// ---------------------------------------------------------------------------
// k_final: merge 8 chunk-partials per batch, build pooled[640], classifier
// grid 32 (one per batch), 128 threads (t = d)
// ---------------------------------------------------------------------------
__global__ __launch_bounds__(128) void k_final(const float* __restrict__ part,
                                               const float* __restrict__ Wc,
                                               float* __restrict__ out) {
  __shared__ float pooled[640];
  __shared__ float r0s[2], r1s[2];
  const int b = blockIdx.x, t = threadIdx.x;
  const float* pb = part + (size_t)b*8*PART_STRIDE;
  float L = -3.0e38f;
#pragma unroll
  for (int c = 0; c < 8; ++c) L = fmaxf(L, pb[c*PART_STRIDE]);
  float S = 0.f, V = 0.f;
  float mh = -3.0e38f, nh = 3.0e38f, mc = -3.0e38f, mhc = -3.0e38f, mm = -3.0e38f;
#pragma unroll
  for (int c = 0; c < 8; ++c) {
    const float* p = pb + c*PART_STRIDE;
    float e = __expf(p[0] - L);
    S += p[1]*e;
    V += p[2 + t]*e;
    mh  = fmaxf(mh,  p[130 + t]);
    nh  = fminf(nh,  p[258 + t]);
    mc  = fmaxf(mc,  p[386 + t]);
    mhc = fmaxf(mhc, p[514 + t]);
    mm  = fmaxf(mm,  p[642 + t]);
  }
  float q2c = V / S;
  pooled[t]       = mh;                               // H section
  pooled[128 + t] = mc;                               // c2q section
  pooled[256 + t] = mhc;                              // H*c2q section
  pooled[384 + t] = (q2c >= 0.f) ? q2c*mh : q2c*nh;   // H*q2c section
  pooled[512 + t] = mm;                               // M section
  __syncthreads();
  float a0 = 0.f, a1 = 0.f;
#pragma unroll
  for (int k = t; k < 640; k += 128) {
    float pv = pooled[k];
    a0 += pv*Wc[k*2 + 0];
    a1 += pv*Wc[k*2 + 1];
  }
#pragma unroll
  for (int off = 32; off; off >>= 1) {
    a0 += __shfl_xor(a0, off);
    a1 += __shfl_xor(a1, off);
  }
  if ((t & 63) == 0) { r0s[t >> 6] = a0; r1s[t >> 6] = a1; }
  __syncthreads();
  if (t == 0) {
    out[b*2 + 0] = r0s[0] + r1s[0]*0.f + r0s[1];  // placeholder avoided below
  }
  if (t == 0) {
    out[b*2 + 0] = r0s[0] + r0s[1];
    out[b*2 + 1] = r1s[0] + r1s[1];
  }
}

// ---------------------------------------------------------------------------
extern "C" void kernel_launch(void* const* d_in, const int* in_sizes, int n_in,
                              void* d_out, int out_size, void* d_ws, size_t ws_size,
                              hipStream_t stream) {
  const float* H   = (const float*)d_in[0];
  const float* U   = (const float*)d_in[1];
  const float* M   = (const float*)d_in[2];
  const int*   tok = (const int*)d_in[3];
  const float* Wa  = (const float*)d_in[4];
  const float* Wc  = (const float*)d_in[5];
  float* out = (float*)d_out;
  float* wsf = (float*)d_ws;
  float* T    = wsf;
  float* part = wsf + T_SIZE;

  hipLaunchKernelGGL(k_T,     dim3(256), dim3(256), 0, stream, U, Wa, T);
  hipLaunchKernelGGL(k_main,  dim3(256), dim3(512), 0, stream, H, U, M, tok, T, part);
  hipLaunchKernelGGL(k_final, dim3(32),  dim3(128), 0, stream, part, Wc, out);
}